// Round 1
// baseline (23617.839 us; speedup 1.0000x reference)
//
#include <hip/hip_runtime.h>
#include <hip/hip_fp16.h>
#include <math.h>

#define NP 65536
#define MP 512
#define SKI 20
#define NBALL 10

// f32(-1/0.05f) rounds exactly to -20.0f
#define NINV_TAU (-20.0f)
// 1/f32(sqrt(128)) ; sc = 1/sqrt(C)
#define SCF (1.0f / 11.313708305358886719f)
#define SCNT (SCF * NINV_TAU)

// ---------------- helpers ----------------

__device__ __forceinline__ void store_sim(float* p, float v) { *p = v; }
__device__ __forceinline__ void store_sim(__half* p, float v) { *p = __float2half(v); }
__device__ __forceinline__ float load_sim(const float* p) { return *p; }
__device__ __forceinline__ float load_sim(const __half* p) { return __half2float(*p); }

__device__ __forceinline__ void lse_add(float& mm, float& ss, float v) {
  if (v <= mm) { ss += __expf(v - mm); }
  else { ss = fmaf(ss, __expf(mm - v), 1.0f); mm = v; }
}
__device__ __forceinline__ void lse_merge(float& mm, float& ss, float om, float os) {
  float nm = fmaxf(mm, om);
  ss = ss * __expf(mm - nm) + os * __expf(om - nm);
  mm = nm;
}

// closed-form symmetric 3x3 eigenvalues (ascending), double precision
__device__ void eig3(double a00, double a01, double a02, double a11, double a12,
                     double a22, double* e) {
  double p1 = a01*a01 + a02*a02 + a12*a12;
  double q  = (a00 + a11 + a22) / 3.0;
  double b00 = a00 - q, b11 = a11 - q, b22 = a22 - q;
  double p2 = b00*b00 + b11*b11 + b22*b22 + 2.0*p1;
  if (p2 <= 1e-300) { e[0] = e[1] = e[2] = q; return; }
  double p = sqrt(p2 / 6.0);
  double ip = 1.0 / p;
  double c00 = b00*ip, c01 = a01*ip, c02 = a02*ip;
  double c11 = b11*ip, c12 = a12*ip, c22 = b22*ip;
  double detB = c00*(c11*c22 - c12*c12) - c01*(c01*c22 - c12*c02)
              + c02*(c01*c12 - c11*c02);
  double r = detB / 2.0;
  r = fmin(1.0, fmax(-1.0, r));
  double phi = acos(r) / 3.0;
  double e2 = q + 2.0*p*cos(phi);
  double e0 = q + 2.0*p*cos(phi + 2.0943951023931953);
  double e1 = 3.0*q - e2 - e0;
  e[0] = e0; e[1] = e1; e[2] = e2;
}

// ---------------- kernels ----------------

// pack xyz + |x|^2 into float4
__global__ void k_prep(const float* __restrict__ xyz, float4* __restrict__ xyzs4) {
  int i = blockIdx.x * blockDim.x + threadIdx.x;
  if (i < NP) {
    float x = xyz[3*i+0], y = xyz[3*i+1], z = xyz[3*i+2];
    xyzs4[i] = make_float4(x, y, z, x*x + y*y + z*z);
  }
}

// farthest point sampling: single workgroup, all state in registers
__global__ __launch_bounds__(1024) void k_fps(const float* __restrict__ xyz,
                                              int* __restrict__ cent) {
  const int t = threadIdx.x;
  float X[64], Y[64], Z[64], D[64];
#pragma unroll
  for (int k = 0; k < 64; ++k) {
    int i = (k << 10) + t;
    X[k] = xyz[3*i+0]; Y[k] = xyz[3*i+1]; Z[k] = xyz[3*i+2];
    D[k] = 1e10f;
  }
  __shared__ float sv[16];
  __shared__ int   si[16];
  __shared__ int   swin;
  int cur = 0;
  float cx = xyz[0], cy = xyz[1], cz = xyz[2];
  const int lane = t & 63, wid = t >> 6;
  for (int it = 0; it < MP; ++it) {
    if (t == 0) cent[it] = cur;
    float bm = -1.0f; int bi = 0x7fffffff;
#pragma unroll
    for (int k = 0; k < 64; ++k) {
      float dx = X[k] - cx, dy = Y[k] - cy, dz = Z[k] - cz;
      float d = dx*dx + dy*dy + dz*dz;
      float nd = fminf(D[k], d);
      D[k] = nd;
      bool gt = (nd > bm);
      bi = gt ? ((k << 10) + t) : bi;
      bm = gt ? nd : bm;
    }
#pragma unroll
    for (int off = 32; off > 0; off >>= 1) {
      float ov = __shfl_down(bm, off);
      int   oi = __shfl_down(bi, off);
      if (ov > bm || (ov == bm && oi < bi)) { bm = ov; bi = oi; }
    }
    if (lane == 0) { sv[wid] = bm; si[wid] = bi; }
    __syncthreads();
    if (t == 0) {
      for (int w = 1; w < 16; ++w)
        if (sv[w] > bm || (sv[w] == bm && si[w] < bi)) { bm = sv[w]; bi = si[w]; }
      swin = bi;
    }
    __syncthreads();
    int win = swin;
    cur = win;
    cx = xyz[3*win+0]; cy = xyz[3*win+1]; cz = xyz[3*win+2];
    __syncthreads();
  }
}

// gather proto xyz (+norm) and mean node
__global__ void k_gather1(const float* __restrict__ xyz, const int* __restrict__ cent,
                          float4* __restrict__ pxyzs4, float* __restrict__ meann) {
  __shared__ float sx[512], sy[512], sz[512];
  int m = threadIdx.x;
  int c = cent[m];
  float x = xyz[3*c+0], y = xyz[3*c+1], z = xyz[3*c+2];
  pxyzs4[m] = make_float4(x, y, z, x*x + y*y + z*z);
  sx[m] = x; sy[m] = y; sz[m] = z;
  __syncthreads();
  for (int off = 256; off > 0; off >>= 1) {
    if (m < off) { sx[m] += sx[m+off]; sy[m] += sy[m+off]; sz[m] += sz[m+off]; }
    __syncthreads();
  }
  if (m == 0) {
    meann[0] = sx[0] * (1.0f/512.0f);
    meann[1] = sy[0] * (1.0f/512.0f);
    meann[2] = sz[0] * (1.0f/512.0f);
  }
}

// gather proto features
__global__ void k_gatherf(const float* __restrict__ feats, const int* __restrict__ cent,
                          float* __restrict__ pf) {
  int m = blockIdx.x, c = threadIdx.x;
  pf[m*128 + c] = feats[(size_t)cent[m]*128 + c];
}

// ball query (first 10 smallest indices within radius) + PCA curvature -> dist_ge
__global__ void k_ballpca(const float4* __restrict__ xyzs4,
                          const float4* __restrict__ pxyzs4,
                          const float* __restrict__ meann,
                          float* __restrict__ ge) {
  const int m = blockIdx.x, t = threadIdx.x;
  __shared__ int lidx[256][NBALL];
  __shared__ int s_sel[NBALL];
  __shared__ int s_win;
  __shared__ int s_w4[4];
  float4 q = pxyzs4[m];
  int cnt = 0;
  for (int k = 0; k < 256; ++k) {
    int i = (k << 8) + t;
    float4 p = xyzs4[i];
    float dot = q.x*p.x + q.y*p.y + q.z*p.z;
    float d2 = (q.w + p.w) - 2.0f*dot;
    float d = sqrtf(fmaxf(d2, 0.0f));
    if (!(d > 0.04f) && cnt < NBALL) { lidx[t][cnt] = i; cnt++; }
  }
  __syncthreads();
  int hp = 0;
  for (int r = 0; r < NBALL; ++r) {
    int v = (hp < cnt) ? lidx[t][hp] : 0x7fffffff;
#pragma unroll
    for (int off = 32; off > 0; off >>= 1) v = min(v, __shfl_down(v, off));
    if ((t & 63) == 0) s_w4[t >> 6] = v;
    __syncthreads();
    if (t == 0) s_win = min(min(s_w4[0], s_w4[1]), min(s_w4[2], s_w4[3]));
    __syncthreads();
    int w = s_win;
    if (w != 0x7fffffff && hp < cnt && lidx[t][hp] == w) hp++;
    if (t == 0) s_sel[r] = w;
    __syncthreads();
  }
  if (t == 0) {
    float mx = meann[0], my = meann[1], mz = meann[2];
    int first = (s_sel[0] != 0x7fffffff) ? s_sel[0] : NP;
    float c00=0,c01=0,c02=0,c11=0,c12=0,c22=0;
    for (int r = 0; r < NBALL; ++r) {
      int id = s_sel[r];
      if (id == 0x7fffffff) id = first;
      float nx, ny, nz;
      if (id >= NP) { nx = mx; ny = my; nz = mz; }
      else { float4 p = xyzs4[id]; nx = p.x; ny = p.y; nz = p.z; }
      float dx = nx - q.x, dy = ny - q.y, dz = nz - q.z;
      c00 += dx*dx; c01 += dx*dy; c02 += dx*dz;
      c11 += dy*dy; c12 += dy*dz; c22 += dz*dz;
    }
    double e[3];
    eig3((double)(c00/10.0f + 1e-8f), (double)(c01/10.0f + 1e-8f),
         (double)(c02/10.0f + 1e-8f), (double)(c11/10.0f + 1e-8f),
         (double)(c12/10.0f + 1e-8f), (double)(c22/10.0f + 1e-8f), e);
    float l0 = (float)e[0], l1 = (float)e[1], l2r = (float)e[2];
    float l2 = fmaxf(l2r, 1e-8f);
    float f0 = (l2 - l1) / l2, f1 = (l1 - l0) / l2, f2 = l0 / l2;
    ge[m] = sqrtf(f0*f0 + f1*f1 + f2*f2) / sqrtf(3.0f);
  }
}

__global__ void k_zero_c(float* __restrict__ c) { c[threadIdx.x] = 0.0f; }

// sinkhorn1 row pass: r_i = -LSE_j( K_ij + c_j ), K recomputed from geometry
__global__ void k_row1(const float4* __restrict__ xyzs4,
                       const float4* __restrict__ pxyzs4,
                       const float* __restrict__ ge, const float* __restrict__ c,
                       float* __restrict__ r) {
  __shared__ float4 sp[MP];
  __shared__ float  su[MP];
  const int t = threadIdx.x;
  for (int j = t; j < MP; j += 256) {
    sp[j] = pxyzs4[j];
    su[j] = fmaf(ge[j], NINV_TAU, c[j]);
  }
  __syncthreads();
  int gid = blockIdx.x*256 + t;
  int i = gid >> 1, h = gid & 1;
  float4 q = xyzs4[i];
  float mm, ss;
  if (h == 0) { mm = 0.0f; ss = 1.0f; } else { mm = -1e30f; ss = 0.0f; }
  int j0 = h << 8;
  for (int j = j0; j < j0 + 256; ++j) {
    float4 p = sp[j];
    float dot = q.x*p.x + q.y*p.y + q.z*p.z;
    float dist = sqrtf(fmaxf((q.w + p.w) - 2.0f*dot, 0.0f));
    float v = fmaf(dist, SCNT, su[j]);
    lse_add(mm, ss, v);
  }
  float om = __shfl_xor(mm, 1);
  float os = __shfl_xor(ss, 1);
  lse_merge(mm, ss, om, os);
  if (h == 0) r[i] = -(mm + __logf(ss));
}

// sinkhorn1 col pass: 2 columns per block
__global__ void k_col1(const float4* __restrict__ xyzs4,
                       const float4* __restrict__ pxyzs4,
                       const float* __restrict__ ge, const float* __restrict__ r,
                       float* __restrict__ c) {
  const int t = threadIdx.x;
  const int j0 = blockIdx.x * 2;
  __shared__ float red[4][4];
  float4 p0 = pxyzs4[j0], p1 = pxyzs4[j0+1];
  float g0 = ge[j0] * NINV_TAU, g1 = ge[j0+1] * NINV_TAU;
  float m0 = -1e30f, s0 = 0.0f, m1 = -1e30f, s1 = 0.0f;
  for (int k = 0; k < 256; ++k) {
    int i = (k << 8) + t;
    float4 q = xyzs4[i];
    float ri = r[i];
    {
      float dot = q.x*p0.x + q.y*p0.y + q.z*p0.z;
      float dist = sqrtf(fmaxf((q.w + p0.w) - 2.0f*dot, 0.0f));
      lse_add(m0, s0, fmaf(dist, SCNT, ri + g0));
    }
    {
      float dot = q.x*p1.x + q.y*p1.y + q.z*p1.z;
      float dist = sqrtf(fmaxf((q.w + p1.w) - 2.0f*dot, 0.0f));
      lse_add(m1, s1, fmaf(dist, SCNT, ri + g1));
    }
  }
#pragma unroll
  for (int off = 32; off > 0; off >>= 1) {
    float am = __shfl_down(m0, off), as = __shfl_down(s0, off);
    float bm = __shfl_down(m1, off), bs = __shfl_down(s1, off);
    lse_merge(m0, s0, am, as);
    lse_merge(m1, s1, bm, bs);
  }
  int lane = t & 63, wid = t >> 6;
  if (lane == 0) { red[wid][0] = m0; red[wid][1] = s0; red[wid][2] = m1; red[wid][3] = s1; }
  __syncthreads();
  if (t == 0) {
    float M0 = red[0][0], S0 = red[0][1], M1 = red[0][2], S1 = red[0][3];
    for (int w = 1; w < 4; ++w) {
      lse_merge(M0, S0, red[w][0], red[w][1]);
      lse_merge(M1, S1, red[w][2], red[w][3]);
    }
    lse_merge(M0, S0, 0.0f, 1.0f);   // pad row
    lse_merge(M1, S1, 0.0f, 1.0f);
    c[j0]   = -(M0 + __logf(S0));
    c[j0+1] = -(M1 + __logf(S1));
  }
}

// partial gamma^T @ feats : grid (64 n-chunks, 8 m-tiles), 128 threads
__global__ void k_pfeat_part(const float4* __restrict__ xyzs4,
                             const float4* __restrict__ pxyzs4,
                             const float* __restrict__ ge, const float* __restrict__ c,
                             const float* __restrict__ r, const float* __restrict__ feats,
                             float* __restrict__ part) {
  const int t = threadIdx.x;
  const int nc = blockIdx.x;
  const int mt = blockIdx.y;
  __shared__ float4 spp[64];
  __shared__ float  ssu[64];
  __shared__ float  sf[64][128];
  __shared__ float  sw[64][64];
  __shared__ float  srr[64];
  if (t < 64) {
    int j = mt*64 + t;
    spp[t] = pxyzs4[j];
    ssu[t] = fmaf(ge[j], NINV_TAU, c[j]);
  }
  const int mg = t >> 4;
  const int cg = t & 15;
  float acc[8][8];
#pragma unroll
  for (int a = 0; a < 8; ++a)
#pragma unroll
    for (int b = 0; b < 8; ++b) acc[a][b] = 0.0f;
  for (int bt = 0; bt < 16; ++bt) {
    int n0 = nc*1024 + bt*64;
    __syncthreads();
    for (int q2 = t; q2 < 2048; q2 += 128) {
      int row = q2 >> 5, c4 = q2 & 31;
      ((float4*)&sf[row][0])[c4] = ((const float4*)feats)[(size_t)(n0+row)*32 + c4];
    }
    if (t < 64) srr[t] = r[n0 + t];
    __syncthreads();
    for (int q2 = t; q2 < 4096; q2 += 128) {
      int nl = q2 >> 6, ml = q2 & 63;
      float4 qv = xyzs4[n0 + nl];
      float4 p = spp[ml];
      float dot = qv.x*p.x + qv.y*p.y + qv.z*p.z;
      float dist = sqrtf(fmaxf((qv.w + p.w) - 2.0f*dot, 0.0f));
      sw[nl][ml] = __expf(fmaf(dist, SCNT, ssu[ml] + srr[nl]));
    }
    __syncthreads();
#pragma unroll 8
    for (int n = 0; n < 64; ++n) {
      float4 w0 = ((float4*)&sw[n][0])[mg*2];
      float4 w1 = ((float4*)&sw[n][0])[mg*2+1];
      float4 f0 = ((float4*)&sf[n][0])[cg*2];
      float4 f1 = ((float4*)&sf[n][0])[cg*2+1];
      float wv[8] = {w0.x,w0.y,w0.z,w0.w,w1.x,w1.y,w1.z,w1.w};
      float fv[8] = {f0.x,f0.y,f0.z,f0.w,f1.x,f1.y,f1.z,f1.w};
#pragma unroll
      for (int a = 0; a < 8; ++a)
#pragma unroll
        for (int b = 0; b < 8; ++b) acc[a][b] = fmaf(wv[a], fv[b], acc[a][b]);
    }
  }
  for (int a = 0; a < 8; ++a) {
    int m = mt*64 + mg*8 + a;
    float* dst = &part[((size_t)nc*MP + m)*128 + cg*8];
    ((float4*)dst)[0] = make_float4(acc[a][0], acc[a][1], acc[a][2], acc[a][3]);
    ((float4*)dst)[1] = make_float4(acc[a][4], acc[a][5], acc[a][6], acc[a][7]);
  }
}

__global__ void k_pfeat_red(const float* __restrict__ part, const float* __restrict__ pf,
                            float* __restrict__ p1) {
  int idx = blockIdx.x*256 + threadIdx.x;
  float s = 0.0f;
  for (int ncb = 0; ncb < 64; ++ncb) s += part[(size_t)ncb*MP*128 + idx];
  p1[idx] = 0.5f*pf[idx] + 0.5f*s;
}

// sim column + top-20 aggregation -> p2
__global__ void k_simtopk(const float* __restrict__ p1, float* __restrict__ p2) {
  const int m = blockIdx.x, t = threadIdx.x;
  __shared__ float spm[128];
  __shared__ float scol[MP];
  __shared__ float sval[20];
  __shared__ int   sid[20];
  __shared__ float sredv[2];
  __shared__ int   sredi[2];
  __shared__ float sden;
  spm[t] = p1[m*128 + t];
  __syncthreads();
  for (int kk = t; kk < MP; kk += 128) {
    float a = 0.0f;
    const float* row = &p1[kk*128];
#pragma unroll 8
    for (int c2 = 0; c2 < 128; ++c2) a = fmaf(row[c2], spm[c2], a);
    scol[kk] = a * SCF;
  }
  __syncthreads();
  for (int rs = 0; rs < 20; ++rs) {
    float bv = -1e30f; int bI = 1 << 30;
    for (int kk = t; kk < MP; kk += 128) {
      float v = scol[kk];
      if (v > bv) { bv = v; bI = kk; }
    }
#pragma unroll
    for (int off = 32; off > 0; off >>= 1) {
      float ov = __shfl_down(bv, off); int oi = __shfl_down(bI, off);
      if (ov > bv || (ov == bv && oi < bI)) { bv = ov; bI = oi; }
    }
    if ((t & 63) == 0) { sredv[t>>6] = bv; sredi[t>>6] = bI; }
    __syncthreads();
    if (t == 0) {
      float v1 = sredv[1]; int i1 = sredi[1];
      if (v1 > bv || (v1 == bv && i1 < bI)) { bv = v1; bI = i1; }
      sval[rs] = bv; sid[rs] = bI;
      scol[bI] = -1e30f;
    }
    __syncthreads();
  }
  if (t == 0) {
    float s = 0.0f;
    for (int rs = 0; rs < 20; ++rs) s += sval[rs];
    sden = fmaxf(s, 1e-4f);
  }
  __syncthreads();
  float a = 0.0f;
  float den = sden;
  for (int rs = 0; rs < 20; ++rs) {
    float w = sval[rs] / den;
    a = fmaf(w, p1[sid[rs]*128 + t], a);
  }
  p2[m*128 + t] = 0.5f*p1[m*128 + t] + 0.5f*a;
}

// sim_pt = feats @ p2^T * sc  : grid (1024, 8), block 256, tile 64x64, K staged in halves
template <typename ST>
__global__ void k_simpt(const float* __restrict__ feats, const float* __restrict__ p2,
                        ST* __restrict__ sim) {
  const int t = threadIdx.x;
  const int nt = blockIdx.x;
  const int mt = blockIdx.y;
  __shared__ float sa[64][68];
  __shared__ float sb[64][68];
  const int tn = t >> 4, tm = t & 15;
  float acc[4][4];
#pragma unroll
  for (int x = 0; x < 4; ++x)
#pragma unroll
    for (int y = 0; y < 4; ++y) acc[x][y] = 0.0f;
  for (int kh = 0; kh < 2; ++kh) {
    __syncthreads();
    for (int q2 = t; q2 < 1024; q2 += 256) {
      int row = q2 >> 4, c4 = q2 & 15;
      ((float4*)&sa[row][0])[c4] =
          ((const float4*)feats)[(size_t)(nt*64+row)*32 + kh*16 + c4];
      ((float4*)&sb[row][0])[c4] =
          ((const float4*)p2)[(size_t)(mt*64+row)*32 + kh*16 + c4];
    }
    __syncthreads();
    for (int k = 0; k < 64; ++k) {
      float av[4], bv[4];
#pragma unroll
      for (int x = 0; x < 4; ++x) av[x] = sa[tn*4+x][k];
#pragma unroll
      for (int y = 0; y < 4; ++y) bv[y] = sb[tm*4+y][k];
#pragma unroll
      for (int x = 0; x < 4; ++x)
#pragma unroll
        for (int y = 0; y < 4; ++y) acc[x][y] = fmaf(av[x], bv[y], acc[x][y]);
    }
  }
  for (int x = 0; x < 4; ++x)
    for (int y = 0; y < 4; ++y) {
      int n = nt*64 + tn*4 + x, mc = mt*64 + tm*4 + y;
      store_sim(&sim[(size_t)n*MP + mc], acc[x][y] * SCF);
    }
}

// sinkhorn2 row pass
template <typename ST>
__global__ void k_row2(const ST* __restrict__ sim, const float* __restrict__ c,
                       float* __restrict__ r) {
  __shared__ float sc_[MP];
  const int t = threadIdx.x;
  for (int j = t; j < MP; j += 256) sc_[j] = c[j];
  __syncthreads();
  int gid = blockIdx.x*256 + t;
  int i = gid >> 1, h = gid & 1;
  float mm, ss;
  if (h == 0) { mm = 0.0f; ss = 1.0f; } else { mm = -1e30f; ss = 0.0f; }
  const ST* row = &sim[(size_t)i*MP + (h << 8)];
  int j0 = h << 8;
  for (int jj = 0; jj < 256; ++jj) {
    float v = fmaf(load_sim(&row[jj]), NINV_TAU, sc_[j0 + jj]);
    lse_add(mm, ss, v);
  }
  float om = __shfl_xor(mm, 1);
  float os = __shfl_xor(ss, 1);
  lse_merge(mm, ss, om, os);
  if (h == 0) r[i] = -(mm + __logf(ss));
}

// sinkhorn2 col pass: transpose via LDS, partial LSE per (rowchunk, col)
template <typename ST>
__global__ void k_col2a(const ST* __restrict__ sim, const float* __restrict__ r,
                        float2* __restrict__ part) {
  const int g = blockIdx.x;   // 0..3 col group of 128
  const int rc = blockIdx.y;  // 0..63 row chunk of 1024
  const int t = threadIdx.x;
  __shared__ float st[64][132];
  __shared__ float sr2[64];
  __shared__ float smm[128], sss[128];
  const int cl = t & 127, hh = t >> 7;
  float mm = -1e30f, ss = 0.0f;
  for (int sb = 0; sb < 16; ++sb) {
    int r0 = rc*1024 + sb*64;
    __syncthreads();
    for (int q2 = t; q2 < 8192; q2 += 256) {
      int row = q2 >> 7, cc = q2 & 127;
      st[row][cc] = load_sim(&sim[(size_t)(r0+row)*MP + g*128 + cc]);
    }
    if (t < 64) sr2[t] = r[r0 + t];
    __syncthreads();
    for (int rr = hh; rr < 64; rr += 2) {
      float v = fmaf(st[rr][cl], NINV_TAU, sr2[rr]);
      lse_add(mm, ss, v);
    }
  }
  if (hh == 1) { smm[cl] = mm; sss[cl] = ss; }
  __syncthreads();
  if (hh == 0) {
    lse_merge(mm, ss, smm[cl], sss[cl]);
    part[(size_t)rc*MP + g*128 + cl] = make_float2(mm, ss);
  }
}

__global__ void k_col2b(const float2* __restrict__ part, float* __restrict__ c) {
  int j = blockIdx.x*256 + threadIdx.x;
  float mm = -1e30f, ss = 0.0f;
  for (int rc = 0; rc < 64; ++rc) {
    float2 p = part[(size_t)rc*MP + j];
    lse_merge(mm, ss, p.x, p.y);
  }
  lse_merge(mm, ss, 0.0f, 1.0f);  // pad row
  c[j] = -(mm + __logf(ss));
}

// refined = 0.5*feats + 0.5 * w @ p2  (w = exp(K + r + c) recomputed)
template <typename ST>
__global__ void k_refined(const ST* __restrict__ sim, const float* __restrict__ r,
                          const float* __restrict__ c, const float* __restrict__ p2,
                          const float* __restrict__ feats, float* __restrict__ out) {
  const int t = threadIdx.x;
  const int nb = blockIdx.x;  // 64 rows per block
  __shared__ float sp[64][128];
  __shared__ float sw[64][68];
  __shared__ float srr[64], scc[64];
  const int tn = t >> 5, tc = t & 31;
  if (t < 64) srr[t] = r[nb*64 + t];
  float acc[8][4];
#pragma unroll
  for (int a = 0; a < 8; ++a)
#pragma unroll
    for (int b = 0; b < 4; ++b) acc[a][b] = 0.0f;
  for (int mt2 = 0; mt2 < 8; ++mt2) {
    __syncthreads();
    for (int q2 = t; q2 < 2048; q2 += 256) {
      int row = q2 >> 5, c4 = q2 & 31;
      ((float4*)&sp[row][0])[c4] = ((const float4*)p2)[(size_t)(mt2*64+row)*32 + c4];
    }
    if (t < 64) scc[t] = c[mt2*64 + t];
    __syncthreads();
    for (int q2 = t; q2 < 4096; q2 += 256) {
      int nl = q2 >> 6, ml = q2 & 63;
      float v = fmaf(load_sim(&sim[(size_t)(nb*64+nl)*MP + mt2*64 + ml]), NINV_TAU,
                     srr[nl] + scc[ml]);
      sw[nl][ml] = __expf(v);
    }
    __syncthreads();
    for (int mm2 = 0; mm2 < 64; ++mm2) {
      float4 pv = ((float4*)&sp[mm2][0])[tc];
      float wv[8];
#pragma unroll
      for (int a = 0; a < 8; ++a) wv[a] = sw[tn*8+a][mm2];
#pragma unroll
      for (int a = 0; a < 8; ++a) {
        acc[a][0] = fmaf(wv[a], pv.x, acc[a][0]);
        acc[a][1] = fmaf(wv[a], pv.y, acc[a][1]);
        acc[a][2] = fmaf(wv[a], pv.z, acc[a][2]);
        acc[a][3] = fmaf(wv[a], pv.w, acc[a][3]);
      }
    }
  }
  for (int a = 0; a < 8; ++a) {
    int row = nb*64 + tn*8 + a;
    float4 f = ((const float4*)feats)[(size_t)row*32 + tc];
    float4 o;
    o.x = 0.5f*f.x + 0.5f*acc[a][0];
    o.y = 0.5f*f.y + 0.5f*acc[a][1];
    o.z = 0.5f*f.z + 0.5f*acc[a][2];
    o.w = 0.5f*f.w + 0.5f*acc[a][3];
    ((float4*)out)[(size_t)row*32 + tc] = o;
  }
}

// ---------------- launcher ----------------

extern "C" void kernel_launch(void* const* d_in, const int* in_sizes, int n_in,
                              void* d_out, int out_size, void* d_ws, size_t ws_size,
                              hipStream_t stream) {
  (void)in_sizes; (void)n_in; (void)out_size;
  const float* xyz   = (const float*)d_in[0];
  const float* feats = (const float*)d_in[1];
  float* out = (float*)d_out;
  char* ws = (char*)d_ws;

  auto al = [](size_t x) { return (x + 255) & ~(size_t)255; };
  size_t simBytesF = (size_t)NP * MP * 4;
  size_t simBytesH = (size_t)NP * MP * 2;
  auto total_for = [&](size_t simB) {
    size_t o = al(simB);
    o += al((size_t)NP * 16);       // xyzs4
    o += al((size_t)NP * 4);        // r
    o += al((size_t)MP * 4);        // c
    o += al((size_t)MP * 4);        // cent
    o += al((size_t)MP * 16);       // pxyzs4
    o += al((size_t)MP * 4);        // ge
    o += al((size_t)256);           // meann
    o += al((size_t)MP * 128 * 4);  // pf
    o += al((size_t)MP * 128 * 4);  // p1
    o += al((size_t)MP * 128 * 4);  // p2
    o += al((size_t)64 * MP * 8);   // part2
    return o;
  };
  bool useHalf = ws_size < total_for(simBytesF);
  size_t simB = useHalf ? simBytesH : simBytesF;

  size_t o = al(simB);
  float4* xyzs4 = (float4*)(ws + o); o += al((size_t)NP * 16);
  float* rbuf   = (float*)(ws + o);  o += al((size_t)NP * 4);
  float* cbuf   = (float*)(ws + o);  o += al((size_t)MP * 4);
  int*   cent   = (int*)(ws + o);    o += al((size_t)MP * 4);
  float4* pxyzs4 = (float4*)(ws + o); o += al((size_t)MP * 16);
  float* ge     = (float*)(ws + o);  o += al((size_t)MP * 4);
  float* meann  = (float*)(ws + o);  o += al((size_t)256);
  float* pf     = (float*)(ws + o);  o += al((size_t)MP * 128 * 4);
  float* p1     = (float*)(ws + o);  o += al((size_t)MP * 128 * 4);
  float* p2     = (float*)(ws + o);  o += al((size_t)MP * 128 * 4);
  float2* part2 = (float2*)(ws + o); o += al((size_t)64 * MP * 8);
  float* partA  = (float*)ws;  // 16MB, overlaps sim region (sim written later)

  k_prep<<<dim3(256), dim3(256), 0, stream>>>(xyz, xyzs4);
  k_fps<<<dim3(1), dim3(1024), 0, stream>>>(xyz, cent);
  k_gather1<<<dim3(1), dim3(512), 0, stream>>>(xyz, cent, pxyzs4, meann);
  k_gatherf<<<dim3(512), dim3(128), 0, stream>>>(feats, cent, pf);
  k_ballpca<<<dim3(512), dim3(256), 0, stream>>>(xyzs4, pxyzs4, meann, ge);

  // sinkhorn 1 (cost recomputed from geometry)
  k_zero_c<<<dim3(1), dim3(512), 0, stream>>>(cbuf);
  for (int it = 0; it < SKI; ++it) {
    k_row1<<<dim3(512), dim3(256), 0, stream>>>(xyzs4, pxyzs4, ge, cbuf, rbuf);
    k_col1<<<dim3(256), dim3(256), 0, stream>>>(xyzs4, pxyzs4, ge, rbuf, cbuf);
  }

  // p1 = 0.5*pf + 0.5*gamma^T feats
  k_pfeat_part<<<dim3(64, 8), dim3(128), 0, stream>>>(xyzs4, pxyzs4, ge, cbuf, rbuf,
                                                      feats, partA);
  k_pfeat_red<<<dim3(256), dim3(256), 0, stream>>>(partA, pf, p1);

  // sim + top-20 aggregation -> p2
  k_simtopk<<<dim3(512), dim3(128), 0, stream>>>(p1, p2);

  if (useHalf) {
    __half* sim = (__half*)ws;
    k_simpt<__half><<<dim3(1024, 8), dim3(256), 0, stream>>>(feats, p2, sim);
    k_zero_c<<<dim3(1), dim3(512), 0, stream>>>(cbuf);
    for (int it = 0; it < SKI; ++it) {
      k_row2<__half><<<dim3(512), dim3(256), 0, stream>>>(sim, cbuf, rbuf);
      k_col2a<__half><<<dim3(4, 64), dim3(256), 0, stream>>>(sim, rbuf, part2);
      k_col2b<<<dim3(2), dim3(256), 0, stream>>>(part2, cbuf);
    }
    k_refined<__half><<<dim3(1024), dim3(256), 0, stream>>>(sim, rbuf, cbuf, p2, feats, out);
  } else {
    float* sim = (float*)ws;
    k_simpt<float><<<dim3(1024, 8), dim3(256), 0, stream>>>(feats, p2, sim);
    k_zero_c<<<dim3(1), dim3(512), 0, stream>>>(cbuf);
    for (int it = 0; it < SKI; ++it) {
      k_row2<float><<<dim3(512), dim3(256), 0, stream>>>(sim, cbuf, rbuf);
      k_col2a<float><<<dim3(4, 64), dim3(256), 0, stream>>>(sim, rbuf, part2);
      k_col2b<<<dim3(2), dim3(256), 0, stream>>>(part2, cbuf);
    }
    k_refined<float><<<dim3(1024), dim3(256), 0, stream>>>(sim, rbuf, cbuf, p2, feats, out);
  }
}

// Round 2
// 11086.166 us; speedup vs baseline: 2.1304x; 2.1304x over previous
//
#include <hip/hip_runtime.h>
#include <hip/hip_fp16.h>
#include <math.h>

#define NP 65536
#define MP 512
#define SKI 20
#define NBALL 10

#define FPS_NBLK 64
#define FPS_NTHR 256

// f32(-1/0.05f) rounds exactly to -20.0f
#define NINV_TAU (-20.0f)
// 1/f32(sqrt(128)) ; sc = 1/sqrt(C)
#define SCF (1.0f / 11.313708305358886719f)
#define SCNT (SCF * NINV_TAU)

// ---------------- helpers ----------------

__device__ __forceinline__ void store_sim(float* p, float v) { *p = v; }
__device__ __forceinline__ void store_sim(__half* p, float v) { *p = __float2half(v); }
__device__ __forceinline__ float load_sim(const float* p) { return *p; }
__device__ __forceinline__ float load_sim(const __half* p) { return __half2float(*p); }

__device__ __forceinline__ void lse_add(float& mm, float& ss, float v) {
  if (v <= mm) { ss += __expf(v - mm); }
  else { ss = fmaf(ss, __expf(mm - v), 1.0f); mm = v; }
}
__device__ __forceinline__ void lse_merge(float& mm, float& ss, float om, float os) {
  float nm = fmaxf(mm, om);
  ss = ss * __expf(mm - nm) + os * __expf(om - nm);
  mm = nm;
}

// closed-form symmetric 3x3 eigenvalues (ascending), double precision
__device__ void eig3(double a00, double a01, double a02, double a11, double a12,
                     double a22, double* e) {
  double p1 = a01*a01 + a02*a02 + a12*a12;
  double q  = (a00 + a11 + a22) / 3.0;
  double b00 = a00 - q, b11 = a11 - q, b22 = a22 - q;
  double p2 = b00*b00 + b11*b11 + b22*b22 + 2.0*p1;
  if (p2 <= 1e-300) { e[0] = e[1] = e[2] = q; return; }
  double p = sqrt(p2 / 6.0);
  double ip = 1.0 / p;
  double c00 = b00*ip, c01 = a01*ip, c02 = a02*ip;
  double c11 = b11*ip, c12 = a12*ip, c22 = b22*ip;
  double detB = c00*(c11*c22 - c12*c12) - c01*(c01*c22 - c12*c02)
              + c02*(c01*c12 - c11*c02);
  double r = detB / 2.0;
  r = fmin(1.0, fmax(-1.0, r));
  double phi = acos(r) / 3.0;
  double e2 = q + 2.0*p*cos(phi);
  double e0 = q + 2.0*p*cos(phi + 2.0943951023931953);
  double e1 = 3.0*q - e2 - e0;
  e[0] = e0; e[1] = e1; e[2] = e2;
}

// ---------------- kernels ----------------

// pack xyz + |x|^2 into float4
__global__ void k_prep(const float* __restrict__ xyz, float4* __restrict__ xyzs4) {
  int i = blockIdx.x * blockDim.x + threadIdx.x;
  if (i < NP) {
    float x = xyz[3*i+0], y = xyz[3*i+1], z = xyz[3*i+2];
    xyzs4[i] = make_float4(x, y, z, x*x + y*y + z*z);
  }
}

// multi-block farthest point sampling: 64 blocks x 256 threads, 4 pts/thread,
// per-iteration device-scope barrier via cnt[it]; slots double-buffered on parity.
__global__ __launch_bounds__(FPS_NTHR) void k_fps2(const float4* __restrict__ xyzs4,
                                                   int* __restrict__ cent,
                                                   unsigned long long* __restrict__ slots,
                                                   int* __restrict__ cnt) {
  const int t = threadIdx.x, b = blockIdx.x;
  const int base = (b * FPS_NTHR + t) * 4;
  float X[4], Y[4], Z[4], D[4];
#pragma unroll
  for (int k = 0; k < 4; ++k) {
    float4 p = xyzs4[base + k];
    X[k] = p.x; Y[k] = p.y; Z[k] = p.z; D[k] = 1e10f;
  }
  __shared__ unsigned long long swave[4];
  __shared__ unsigned long long swin;
  int cur = 0;
  float cx = xyzs4[0].x, cy = xyzs4[0].y, cz = xyzs4[0].z;
  const int lane = t & 63, wid = t >> 6;
  for (int it = 0; it < MP; ++it) {
    if (b == 0 && t == 0) cent[it] = cur;
    float bm = -1.0f; int bi = 0x7fffffff;
#pragma unroll
    for (int k = 0; k < 4; ++k) {
      float dx = X[k] - cx, dy = Y[k] - cy, dz = Z[k] - cz;
      float d = dx*dx + dy*dy + dz*dz;
      float nd = fminf(D[k], d);
      D[k] = nd;
      bool gt = (nd > bm);
      bi = gt ? (base + k) : bi;
      bm = gt ? nd : bm;
    }
    // pack: (dist bits desc, idx asc) -> max key wins; dist >= 0 so bits monotone
    unsigned long long key =
        ((unsigned long long)__float_as_uint(bm) << 32) |
        (unsigned int)(0x7fffffff - bi);
#pragma unroll
    for (int off = 32; off > 0; off >>= 1) {
      unsigned long long o = __shfl_down(key, off);
      key = (o > key) ? o : key;
    }
    if (lane == 0) swave[wid] = key;
    __syncthreads();
    if (t == 0) {
      unsigned long long k0 = swave[0];
      for (int w = 1; w < 4; ++w) k0 = (swave[w] > k0) ? swave[w] : k0;
      atomicExch(&slots[(it & 1) * FPS_NBLK + b], k0);
      __threadfence();
      atomicAdd(&cnt[it], 1);
      while (atomicAdd(&cnt[it], 0) < FPS_NBLK) { __builtin_amdgcn_s_sleep(8); }
    }
    __syncthreads();
    if (wid == 0) {
      unsigned long long k2 = atomicAdd(&slots[(it & 1) * FPS_NBLK + lane], 0ULL);
#pragma unroll
      for (int off = 32; off > 0; off >>= 1) {
        unsigned long long o = __shfl_down(k2, off);
        k2 = (o > k2) ? o : k2;
      }
      if (lane == 0) swin = k2;
    }
    __syncthreads();
    unsigned long long wkey = swin;
    cur = 0x7fffffff - (int)(wkey & 0xffffffffu);
    float4 cc = xyzs4[cur];
    cx = cc.x; cy = cc.y; cz = cc.z;
    __syncthreads();
  }
}

// gather proto xyz (+norm) and mean node
__global__ void k_gather1(const float* __restrict__ xyz, const int* __restrict__ cent,
                          float4* __restrict__ pxyzs4, float* __restrict__ meann) {
  __shared__ float sx[512], sy[512], sz[512];
  int m = threadIdx.x;
  int c = cent[m];
  float x = xyz[3*c+0], y = xyz[3*c+1], z = xyz[3*c+2];
  pxyzs4[m] = make_float4(x, y, z, x*x + y*y + z*z);
  sx[m] = x; sy[m] = y; sz[m] = z;
  __syncthreads();
  for (int off = 256; off > 0; off >>= 1) {
    if (m < off) { sx[m] += sx[m+off]; sy[m] += sy[m+off]; sz[m] += sz[m+off]; }
    __syncthreads();
  }
  if (m == 0) {
    meann[0] = sx[0] * (1.0f/512.0f);
    meann[1] = sy[0] * (1.0f/512.0f);
    meann[2] = sz[0] * (1.0f/512.0f);
  }
}

// gather proto features
__global__ void k_gatherf(const float* __restrict__ feats, const int* __restrict__ cent,
                          float* __restrict__ pf) {
  int m = blockIdx.x, c = threadIdx.x;
  pf[m*128 + c] = feats[(size_t)cent[m]*128 + c];
}

// ball query (first 10 smallest indices within radius) + PCA curvature -> dist_ge
__global__ void k_ballpca(const float4* __restrict__ xyzs4,
                          const float4* __restrict__ pxyzs4,
                          const float* __restrict__ meann,
                          float* __restrict__ ge) {
  const int m = blockIdx.x, t = threadIdx.x;
  __shared__ int lidx[256][NBALL];
  __shared__ int s_sel[NBALL];
  __shared__ int s_win;
  __shared__ int s_w4[4];
  float4 q = pxyzs4[m];
  int cnt = 0;
  for (int k = 0; k < 256; ++k) {
    int i = (k << 8) + t;
    float4 p = xyzs4[i];
    float dot = q.x*p.x + q.y*p.y + q.z*p.z;
    float d2 = (q.w + p.w) - 2.0f*dot;
    float d = sqrtf(fmaxf(d2, 0.0f));
    if (!(d > 0.04f) && cnt < NBALL) { lidx[t][cnt] = i; cnt++; }
  }
  __syncthreads();
  int hp = 0;
  for (int r = 0; r < NBALL; ++r) {
    int v = (hp < cnt) ? lidx[t][hp] : 0x7fffffff;
#pragma unroll
    for (int off = 32; off > 0; off >>= 1) v = min(v, __shfl_down(v, off));
    if ((t & 63) == 0) s_w4[t >> 6] = v;
    __syncthreads();
    if (t == 0) s_win = min(min(s_w4[0], s_w4[1]), min(s_w4[2], s_w4[3]));
    __syncthreads();
    int w = s_win;
    if (w != 0x7fffffff && hp < cnt && lidx[t][hp] == w) hp++;
    if (t == 0) s_sel[r] = w;
    __syncthreads();
  }
  if (t == 0) {
    float mx = meann[0], my = meann[1], mz = meann[2];
    int first = (s_sel[0] != 0x7fffffff) ? s_sel[0] : NP;
    float c00=0,c01=0,c02=0,c11=0,c12=0,c22=0;
    for (int r = 0; r < NBALL; ++r) {
      int id = s_sel[r];
      if (id == 0x7fffffff) id = first;
      float nx, ny, nz;
      if (id >= NP) { nx = mx; ny = my; nz = mz; }
      else { float4 p = xyzs4[id]; nx = p.x; ny = p.y; nz = p.z; }
      float dx = nx - q.x, dy = ny - q.y, dz = nz - q.z;
      c00 += dx*dx; c01 += dx*dy; c02 += dx*dz;
      c11 += dy*dy; c12 += dy*dz; c22 += dz*dz;
    }
    double e[3];
    eig3((double)(c00/10.0f + 1e-8f), (double)(c01/10.0f + 1e-8f),
         (double)(c02/10.0f + 1e-8f), (double)(c11/10.0f + 1e-8f),
         (double)(c12/10.0f + 1e-8f), (double)(c22/10.0f + 1e-8f), e);
    float l0 = (float)e[0], l1 = (float)e[1], l2r = (float)e[2];
    float l2 = fmaxf(l2r, 1e-8f);
    float f0 = (l2 - l1) / l2, f1 = (l1 - l0) / l2, f2 = l0 / l2;
    ge[m] = sqrtf(f0*f0 + f1*f1 + f2*f2) / sqrtf(3.0f);
  }
}

__global__ void k_zero_c(float* __restrict__ c) { c[threadIdx.x] = 0.0f; }

// sinkhorn1 row pass: r_i = -LSE_j( K_ij + c_j ), K recomputed from geometry
__global__ void k_row1(const float4* __restrict__ xyzs4,
                       const float4* __restrict__ pxyzs4,
                       const float* __restrict__ ge, const float* __restrict__ c,
                       float* __restrict__ r) {
  __shared__ float4 sp[MP];
  __shared__ float  su[MP];
  const int t = threadIdx.x;
  for (int j = t; j < MP; j += 256) {
    sp[j] = pxyzs4[j];
    su[j] = fmaf(ge[j], NINV_TAU, c[j]);
  }
  __syncthreads();
  int gid = blockIdx.x*256 + t;
  int i = gid >> 1, h = gid & 1;
  float4 q = xyzs4[i];
  float mm, ss;
  if (h == 0) { mm = 0.0f; ss = 1.0f; } else { mm = -1e30f; ss = 0.0f; }
  int j0 = h << 8;
  for (int j = j0; j < j0 + 256; ++j) {
    float4 p = sp[j];
    float dot = q.x*p.x + q.y*p.y + q.z*p.z;
    float dist = sqrtf(fmaxf((q.w + p.w) - 2.0f*dot, 0.0f));
    float v = fmaf(dist, SCNT, su[j]);
    lse_add(mm, ss, v);
  }
  float om = __shfl_xor(mm, 1);
  float os = __shfl_xor(ss, 1);
  lse_merge(mm, ss, om, os);
  if (h == 0) r[i] = -(mm + __logf(ss));
}

// sinkhorn1 col pass: 2 columns per block
__global__ void k_col1(const float4* __restrict__ xyzs4,
                       const float4* __restrict__ pxyzs4,
                       const float* __restrict__ ge, const float* __restrict__ r,
                       float* __restrict__ c) {
  const int t = threadIdx.x;
  const int j0 = blockIdx.x * 2;
  __shared__ float red[4][4];
  float4 p0 = pxyzs4[j0], p1 = pxyzs4[j0+1];
  float g0 = ge[j0] * NINV_TAU, g1 = ge[j0+1] * NINV_TAU;
  float m0 = -1e30f, s0 = 0.0f, m1 = -1e30f, s1 = 0.0f;
  for (int k = 0; k < 256; ++k) {
    int i = (k << 8) + t;
    float4 q = xyzs4[i];
    float ri = r[i];
    {
      float dot = q.x*p0.x + q.y*p0.y + q.z*p0.z;
      float dist = sqrtf(fmaxf((q.w + p0.w) - 2.0f*dot, 0.0f));
      lse_add(m0, s0, fmaf(dist, SCNT, ri + g0));
    }
    {
      float dot = q.x*p1.x + q.y*p1.y + q.z*p1.z;
      float dist = sqrtf(fmaxf((q.w + p1.w) - 2.0f*dot, 0.0f));
      lse_add(m1, s1, fmaf(dist, SCNT, ri + g1));
    }
  }
#pragma unroll
  for (int off = 32; off > 0; off >>= 1) {
    float am = __shfl_down(m0, off), as = __shfl_down(s0, off);
    float bm = __shfl_down(m1, off), bs = __shfl_down(s1, off);
    lse_merge(m0, s0, am, as);
    lse_merge(m1, s1, bm, bs);
  }
  int lane = t & 63, wid = t >> 6;
  if (lane == 0) { red[wid][0] = m0; red[wid][1] = s0; red[wid][2] = m1; red[wid][3] = s1; }
  __syncthreads();
  if (t == 0) {
    float M0 = red[0][0], S0 = red[0][1], M1 = red[0][2], S1 = red[0][3];
    for (int w = 1; w < 4; ++w) {
      lse_merge(M0, S0, red[w][0], red[w][1]);
      lse_merge(M1, S1, red[w][2], red[w][3]);
    }
    lse_merge(M0, S0, 0.0f, 1.0f);   // pad row
    lse_merge(M1, S1, 0.0f, 1.0f);
    c[j0]   = -(M0 + __logf(S0));
    c[j0+1] = -(M1 + __logf(S1));
  }
}

// partial gamma^T @ feats : grid (64 n-chunks, 8 m-tiles), 128 threads
__global__ void k_pfeat_part(const float4* __restrict__ xyzs4,
                             const float4* __restrict__ pxyzs4,
                             const float* __restrict__ ge, const float* __restrict__ c,
                             const float* __restrict__ r, const float* __restrict__ feats,
                             float* __restrict__ part) {
  const int t = threadIdx.x;
  const int nc = blockIdx.x;
  const int mt = blockIdx.y;
  __shared__ float4 spp[64];
  __shared__ float  ssu[64];
  __shared__ float  sf[64][128];
  __shared__ float  sw[64][64];
  __shared__ float  srr[64];
  if (t < 64) {
    int j = mt*64 + t;
    spp[t] = pxyzs4[j];
    ssu[t] = fmaf(ge[j], NINV_TAU, c[j]);
  }
  const int mg = t >> 4;
  const int cg = t & 15;
  float acc[8][8];
#pragma unroll
  for (int a = 0; a < 8; ++a)
#pragma unroll
    for (int b = 0; b < 8; ++b) acc[a][b] = 0.0f;
  for (int bt = 0; bt < 16; ++bt) {
    int n0 = nc*1024 + bt*64;
    __syncthreads();
    for (int q2 = t; q2 < 2048; q2 += 128) {
      int row = q2 >> 5, c4 = q2 & 31;
      ((float4*)&sf[row][0])[c4] = ((const float4*)feats)[(size_t)(n0+row)*32 + c4];
    }
    if (t < 64) srr[t] = r[n0 + t];
    __syncthreads();
    for (int q2 = t; q2 < 4096; q2 += 128) {
      int nl = q2 >> 6, ml = q2 & 63;
      float4 qv = xyzs4[n0 + nl];
      float4 p = spp[ml];
      float dot = qv.x*p.x + qv.y*p.y + qv.z*p.z;
      float dist = sqrtf(fmaxf((qv.w + p.w) - 2.0f*dot, 0.0f));
      sw[nl][ml] = __expf(fmaf(dist, SCNT, ssu[ml] + srr[nl]));
    }
    __syncthreads();
#pragma unroll 8
    for (int n = 0; n < 64; ++n) {
      float4 w0 = ((float4*)&sw[n][0])[mg*2];
      float4 w1 = ((float4*)&sw[n][0])[mg*2+1];
      float4 f0 = ((float4*)&sf[n][0])[cg*2];
      float4 f1 = ((float4*)&sf[n][0])[cg*2+1];
      float wv[8] = {w0.x,w0.y,w0.z,w0.w,w1.x,w1.y,w1.z,w1.w};
      float fv[8] = {f0.x,f0.y,f0.z,f0.w,f1.x,f1.y,f1.z,f1.w};
#pragma unroll
      for (int a = 0; a < 8; ++a)
#pragma unroll
        for (int b = 0; b < 8; ++b) acc[a][b] = fmaf(wv[a], fv[b], acc[a][b]);
    }
  }
  for (int a = 0; a < 8; ++a) {
    int m = mt*64 + mg*8 + a;
    float* dst = &part[((size_t)nc*MP + m)*128 + cg*8];
    ((float4*)dst)[0] = make_float4(acc[a][0], acc[a][1], acc[a][2], acc[a][3]);
    ((float4*)dst)[1] = make_float4(acc[a][4], acc[a][5], acc[a][6], acc[a][7]);
  }
}

__global__ void k_pfeat_red(const float* __restrict__ part, const float* __restrict__ pf,
                            float* __restrict__ p1) {
  int idx = blockIdx.x*256 + threadIdx.x;
  float s = 0.0f;
  for (int ncb = 0; ncb < 64; ++ncb) s += part[(size_t)ncb*MP*128 + idx];
  p1[idx] = 0.5f*pf[idx] + 0.5f*s;
}

// sim column + top-20 aggregation -> p2
__global__ void k_simtopk(const float* __restrict__ p1, float* __restrict__ p2) {
  const int m = blockIdx.x, t = threadIdx.x;
  __shared__ float spm[128];
  __shared__ float scol[MP];
  __shared__ float sval[20];
  __shared__ int   sid[20];
  __shared__ float sredv[2];
  __shared__ int   sredi[2];
  __shared__ float sden;
  spm[t] = p1[m*128 + t];
  __syncthreads();
  for (int kk = t; kk < MP; kk += 128) {
    float a = 0.0f;
    const float* row = &p1[kk*128];
#pragma unroll 8
    for (int c2 = 0; c2 < 128; ++c2) a = fmaf(row[c2], spm[c2], a);
    scol[kk] = a * SCF;
  }
  __syncthreads();
  for (int rs = 0; rs < 20; ++rs) {
    float bv = -1e30f; int bI = 1 << 30;
    for (int kk = t; kk < MP; kk += 128) {
      float v = scol[kk];
      if (v > bv) { bv = v; bI = kk; }
    }
#pragma unroll
    for (int off = 32; off > 0; off >>= 1) {
      float ov = __shfl_down(bv, off); int oi = __shfl_down(bI, off);
      if (ov > bv || (ov == bv && oi < bI)) { bv = ov; bI = oi; }
    }
    if ((t & 63) == 0) { sredv[t>>6] = bv; sredi[t>>6] = bI; }
    __syncthreads();
    if (t == 0) {
      float v1 = sredv[1]; int i1 = sredi[1];
      if (v1 > bv || (v1 == bv && i1 < bI)) { bv = v1; bI = i1; }
      sval[rs] = bv; sid[rs] = bI;
      scol[bI] = -1e30f;
    }
    __syncthreads();
  }
  if (t == 0) {
    float s = 0.0f;
    for (int rs = 0; rs < 20; ++rs) s += sval[rs];
    sden = fmaxf(s, 1e-4f);
  }
  __syncthreads();
  float a = 0.0f;
  float den = sden;
  for (int rs = 0; rs < 20; ++rs) {
    float w = sval[rs] / den;
    a = fmaf(w, p1[sid[rs]*128 + t], a);
  }
  p2[m*128 + t] = 0.5f*p1[m*128 + t] + 0.5f*a;
}

// sim_pt = feats @ p2^T * sc  : grid (1024, 8), block 256, tile 64x64, K staged in halves
template <typename ST>
__global__ void k_simpt(const float* __restrict__ feats, const float* __restrict__ p2,
                        ST* __restrict__ sim) {
  const int t = threadIdx.x;
  const int nt = blockIdx.x;
  const int mt = blockIdx.y;
  __shared__ float sa[64][68];
  __shared__ float sb[64][68];
  const int tn = t >> 4, tm = t & 15;
  float acc[4][4];
#pragma unroll
  for (int x = 0; x < 4; ++x)
#pragma unroll
    for (int y = 0; y < 4; ++y) acc[x][y] = 0.0f;
  for (int kh = 0; kh < 2; ++kh) {
    __syncthreads();
    for (int q2 = t; q2 < 1024; q2 += 256) {
      int row = q2 >> 4, c4 = q2 & 15;
      ((float4*)&sa[row][0])[c4] =
          ((const float4*)feats)[(size_t)(nt*64+row)*32 + kh*16 + c4];
      ((float4*)&sb[row][0])[c4] =
          ((const float4*)p2)[(size_t)(mt*64+row)*32 + kh*16 + c4];
    }
    __syncthreads();
    for (int k = 0; k < 64; ++k) {
      float av[4], bv[4];
#pragma unroll
      for (int x = 0; x < 4; ++x) av[x] = sa[tn*4+x][k];
#pragma unroll
      for (int y = 0; y < 4; ++y) bv[y] = sb[tm*4+y][k];
#pragma unroll
      for (int x = 0; x < 4; ++x)
#pragma unroll
        for (int y = 0; y < 4; ++y) acc[x][y] = fmaf(av[x], bv[y], acc[x][y]);
    }
  }
  for (int x = 0; x < 4; ++x)
    for (int y = 0; y < 4; ++y) {
      int n = nt*64 + tn*4 + x, mc = mt*64 + tm*4 + y;
      store_sim(&sim[(size_t)n*MP + mc], acc[x][y] * SCF);
    }
}

// sinkhorn2 row pass
template <typename ST>
__global__ void k_row2(const ST* __restrict__ sim, const float* __restrict__ c,
                       float* __restrict__ r) {
  __shared__ float sc_[MP];
  const int t = threadIdx.x;
  for (int j = t; j < MP; j += 256) sc_[j] = c[j];
  __syncthreads();
  int gid = blockIdx.x*256 + t;
  int i = gid >> 1, h = gid & 1;
  float mm, ss;
  if (h == 0) { mm = 0.0f; ss = 1.0f; } else { mm = -1e30f; ss = 0.0f; }
  const ST* row = &sim[(size_t)i*MP + (h << 8)];
  int j0 = h << 8;
  for (int jj = 0; jj < 256; ++jj) {
    float v = fmaf(load_sim(&row[jj]), NINV_TAU, sc_[j0 + jj]);
    lse_add(mm, ss, v);
  }
  float om = __shfl_xor(mm, 1);
  float os = __shfl_xor(ss, 1);
  lse_merge(mm, ss, om, os);
  if (h == 0) r[i] = -(mm + __logf(ss));
}

// sinkhorn2 col pass: transpose via LDS, partial LSE per (rowchunk, col)
template <typename ST>
__global__ void k_col2a(const ST* __restrict__ sim, const float* __restrict__ r,
                        float2* __restrict__ part) {
  const int g = blockIdx.x;   // 0..3 col group of 128
  const int rc = blockIdx.y;  // 0..63 row chunk of 1024
  const int t = threadIdx.x;
  __shared__ float st[64][132];
  __shared__ float sr2[64];
  __shared__ float smm[128], sss[128];
  const int cl = t & 127, hh = t >> 7;
  float mm = -1e30f, ss = 0.0f;
  for (int sb = 0; sb < 16; ++sb) {
    int r0 = rc*1024 + sb*64;
    __syncthreads();
    for (int q2 = t; q2 < 8192; q2 += 256) {
      int row = q2 >> 7, cc = q2 & 127;
      st[row][cc] = load_sim(&sim[(size_t)(r0+row)*MP + g*128 + cc]);
    }
    if (t < 64) sr2[t] = r[r0 + t];
    __syncthreads();
    for (int rr = hh; rr < 64; rr += 2) {
      float v = fmaf(st[rr][cl], NINV_TAU, sr2[rr]);
      lse_add(mm, ss, v);
    }
  }
  if (hh == 1) { smm[cl] = mm; sss[cl] = ss; }
  __syncthreads();
  if (hh == 0) {
    lse_merge(mm, ss, smm[cl], sss[cl]);
    part[(size_t)rc*MP + g*128 + cl] = make_float2(mm, ss);
  }
}

__global__ void k_col2b(const float2* __restrict__ part, float* __restrict__ c) {
  int j = blockIdx.x*256 + threadIdx.x;
  float mm = -1e30f, ss = 0.0f;
  for (int rc = 0; rc < 64; ++rc) {
    float2 p = part[(size_t)rc*MP + j];
    lse_merge(mm, ss, p.x, p.y);
  }
  lse_merge(mm, ss, 0.0f, 1.0f);  // pad row
  c[j] = -(mm + __logf(ss));
}

// refined = 0.5*feats + 0.5 * w @ p2  (w = exp(K + r + c) recomputed)
template <typename ST>
__global__ void k_refined(const ST* __restrict__ sim, const float* __restrict__ r,
                          const float* __restrict__ c, const float* __restrict__ p2,
                          const float* __restrict__ feats, float* __restrict__ out) {
  const int t = threadIdx.x;
  const int nb = blockIdx.x;  // 64 rows per block
  __shared__ float sp[64][128];
  __shared__ float sw[64][68];
  __shared__ float srr[64], scc[64];
  const int tn = t >> 5, tc = t & 31;
  if (t < 64) srr[t] = r[nb*64 + t];
  float acc[8][4];
#pragma unroll
  for (int a = 0; a < 8; ++a)
#pragma unroll
    for (int b = 0; b < 4; ++b) acc[a][b] = 0.0f;
  for (int mt2 = 0; mt2 < 8; ++mt2) {
    __syncthreads();
    for (int q2 = t; q2 < 2048; q2 += 256) {
      int row = q2 >> 5, c4 = q2 & 31;
      ((float4*)&sp[row][0])[c4] = ((const float4*)p2)[(size_t)(mt2*64+row)*32 + c4];
    }
    if (t < 64) scc[t] = c[mt2*64 + t];
    __syncthreads();
    for (int q2 = t; q2 < 4096; q2 += 256) {
      int nl = q2 >> 6, ml = q2 & 63;
      float v = fmaf(load_sim(&sim[(size_t)(nb*64+nl)*MP + mt2*64 + ml]), NINV_TAU,
                     srr[nl] + scc[ml]);
      sw[nl][ml] = __expf(v);
    }
    __syncthreads();
    for (int mm2 = 0; mm2 < 64; ++mm2) {
      float4 pv = ((float4*)&sp[mm2][0])[tc];
      float wv[8];
#pragma unroll
      for (int a = 0; a < 8; ++a) wv[a] = sw[tn*8+a][mm2];
#pragma unroll
      for (int a = 0; a < 8; ++a) {
        acc[a][0] = fmaf(wv[a], pv.x, acc[a][0]);
        acc[a][1] = fmaf(wv[a], pv.y, acc[a][1]);
        acc[a][2] = fmaf(wv[a], pv.z, acc[a][2]);
        acc[a][3] = fmaf(wv[a], pv.w, acc[a][3]);
      }
    }
  }
  for (int a = 0; a < 8; ++a) {
    int row = nb*64 + tn*8 + a;
    float4 f = ((const float4*)feats)[(size_t)row*32 + tc];
    float4 o;
    o.x = 0.5f*f.x + 0.5f*acc[a][0];
    o.y = 0.5f*f.y + 0.5f*acc[a][1];
    o.z = 0.5f*f.z + 0.5f*acc[a][2];
    o.w = 0.5f*f.w + 0.5f*acc[a][3];
    ((float4*)out)[(size_t)row*32 + tc] = o;
  }
}

// ---------------- launcher ----------------

extern "C" void kernel_launch(void* const* d_in, const int* in_sizes, int n_in,
                              void* d_out, int out_size, void* d_ws, size_t ws_size,
                              hipStream_t stream) {
  (void)in_sizes; (void)n_in; (void)out_size;
  const float* xyz   = (const float*)d_in[0];
  const float* feats = (const float*)d_in[1];
  float* out = (float*)d_out;
  char* ws = (char*)d_ws;

  auto al = [](size_t x) { return (x + 255) & ~(size_t)255; };
  size_t simBytesF = (size_t)NP * MP * 4;
  size_t simBytesH = (size_t)NP * MP * 2;
  auto total_for = [&](size_t simB) {
    size_t o = al(simB);
    o += al((size_t)NP * 16);       // xyzs4
    o += al((size_t)NP * 4);        // r
    o += al((size_t)MP * 4);        // c
    o += al((size_t)MP * 4);        // cent
    o += al((size_t)MP * 16);       // pxyzs4
    o += al((size_t)MP * 4);        // ge
    o += al((size_t)256);           // meann
    o += al((size_t)MP * 128 * 4);  // pf
    o += al((size_t)MP * 128 * 4);  // p1
    o += al((size_t)MP * 128 * 4);  // p2
    o += al((size_t)64 * MP * 8);   // part2
    o += al((size_t)MP * 4);        // fps cnt
    o += al((size_t)2 * FPS_NBLK * 8); // fps slots
    return o;
  };
  bool useHalf = ws_size < total_for(simBytesF);
  size_t simB = useHalf ? simBytesH : simBytesF;

  size_t o = al(simB);
  float4* xyzs4 = (float4*)(ws + o); o += al((size_t)NP * 16);
  float* rbuf   = (float*)(ws + o);  o += al((size_t)NP * 4);
  float* cbuf   = (float*)(ws + o);  o += al((size_t)MP * 4);
  int*   cent   = (int*)(ws + o);    o += al((size_t)MP * 4);
  float4* pxyzs4 = (float4*)(ws + o); o += al((size_t)MP * 16);
  float* ge     = (float*)(ws + o);  o += al((size_t)MP * 4);
  float* meann  = (float*)(ws + o);  o += al((size_t)256);
  float* pf     = (float*)(ws + o);  o += al((size_t)MP * 128 * 4);
  float* p1     = (float*)(ws + o);  o += al((size_t)MP * 128 * 4);
  float* p2     = (float*)(ws + o);  o += al((size_t)MP * 128 * 4);
  float2* part2 = (float2*)(ws + o); o += al((size_t)64 * MP * 8);
  int* fcnt     = (int*)(ws + o);    o += al((size_t)MP * 4);
  unsigned long long* fslots = (unsigned long long*)(ws + o);
  o += al((size_t)2 * FPS_NBLK * 8);
  float* partA  = (float*)ws;  // 16MB, overlaps sim region (sim written later)

  k_prep<<<dim3(256), dim3(256), 0, stream>>>(xyz, xyzs4);
  hipMemsetAsync(fcnt, 0, (size_t)MP * 4, stream);
  k_fps2<<<dim3(FPS_NBLK), dim3(FPS_NTHR), 0, stream>>>(xyzs4, cent, fslots, fcnt);
  k_gather1<<<dim3(1), dim3(512), 0, stream>>>(xyz, cent, pxyzs4, meann);
  k_gatherf<<<dim3(512), dim3(128), 0, stream>>>(feats, cent, pf);
  k_ballpca<<<dim3(512), dim3(256), 0, stream>>>(xyzs4, pxyzs4, meann, ge);

  // sinkhorn 1 (cost recomputed from geometry)
  k_zero_c<<<dim3(1), dim3(512), 0, stream>>>(cbuf);
  for (int it = 0; it < SKI; ++it) {
    k_row1<<<dim3(512), dim3(256), 0, stream>>>(xyzs4, pxyzs4, ge, cbuf, rbuf);
    k_col1<<<dim3(256), dim3(256), 0, stream>>>(xyzs4, pxyzs4, ge, rbuf, cbuf);
  }

  // p1 = 0.5*pf + 0.5*gamma^T feats
  k_pfeat_part<<<dim3(64, 8), dim3(128), 0, stream>>>(xyzs4, pxyzs4, ge, cbuf, rbuf,
                                                      feats, partA);
  k_pfeat_red<<<dim3(256), dim3(256), 0, stream>>>(partA, pf, p1);

  // sim + top-20 aggregation -> p2
  k_simtopk<<<dim3(512), dim3(128), 0, stream>>>(p1, p2);

  if (useHalf) {
    __half* sim = (__half*)ws;
    k_simpt<__half><<<dim3(1024, 8), dim3(256), 0, stream>>>(feats, p2, sim);
    k_zero_c<<<dim3(1), dim3(512), 0, stream>>>(cbuf);
    for (int it = 0; it < SKI; ++it) {
      k_row2<__half><<<dim3(512), dim3(256), 0, stream>>>(sim, cbuf, rbuf);
      k_col2a<__half><<<dim3(4, 64), dim3(256), 0, stream>>>(sim, rbuf, part2);
      k_col2b<<<dim3(2), dim3(256), 0, stream>>>(part2, cbuf);
    }
    k_refined<__half><<<dim3(1024), dim3(256), 0, stream>>>(sim, rbuf, cbuf, p2, feats, out);
  } else {
    float* sim = (float*)ws;
    k_simpt<float><<<dim3(1024, 8), dim3(256), 0, stream>>>(feats, p2, sim);
    k_zero_c<<<dim3(1), dim3(512), 0, stream>>>(cbuf);
    for (int it = 0; it < SKI; ++it) {
      k_row2<float><<<dim3(512), dim3(256), 0, stream>>>(sim, cbuf, rbuf);
      k_col2a<float><<<dim3(4, 64), dim3(256), 0, stream>>>(sim, rbuf, part2);
      k_col2b<<<dim3(2), dim3(256), 0, stream>>>(part2, cbuf);
    }
    k_refined<float><<<dim3(1024), dim3(256), 0, stream>>>(sim, rbuf, cbuf, p2, feats, out);
  }
}